// Round 19
// baseline (179.527 us; speedup 1.0000x reference)
//
#include <hip/hip_runtime.h>

typedef unsigned short u16;
typedef unsigned int u32;
typedef u16 u16x8 __attribute__((ext_vector_type(8)));
typedef u16 u16x4 __attribute__((ext_vector_type(4)));
typedef u32 u32x4 __attribute__((ext_vector_type(4)));
typedef __bf16 bf16x8 __attribute__((ext_vector_type(8)));
typedef float f32x4 __attribute__((ext_vector_type(4)));
typedef float f32x16 __attribute__((ext_vector_type(16)));

// ---- helpers -------------------------------------------------------------

static __device__ __forceinline__ u16 bf16_rn(float f) {
    union { float f; u32 u; } a; a.f = f;
    u32 u = a.u;
    return (u16)((u + 0x7FFFu + ((u >> 16) & 1u)) >> 16);  // RNE
}

static __device__ __forceinline__ bf16x8 as_bf(u16x8 v) {
    return __builtin_bit_cast(bf16x8, v);
}

static __device__ __forceinline__ u32 cvt_pk_bf16(float lo, float hi) {
    u32 r;
    asm("v_cvt_pk_bf16_f32 %0, %1, %2" : "=v"(r) : "v"(lo), "v"(hi));
    return r;
}

static __device__ __forceinline__ void glds16(const u16* g, u16* lds) {
    __builtin_amdgcn_global_load_lds(
        (const __attribute__((address_space(1))) void*)g,
        (__attribute__((address_space(3))) void*)lds, 16, 0, 0);
}

// ---- kernel 1: fused preprocessing ----------------------------------------
// bid < 2048        : x f32 -> bf16 (8 elems/thread)
// 2048 <= bid < 5120: w_qkv [1024][3072] -> wqkvT [3072][1024] bf16
// bid >= 5120       : w_out [1024][1024] -> woutT [1024][1024] bf16

__global__ void k_prep(const float* __restrict__ x, u16* __restrict__ xb,
                       const float* __restrict__ w_qkv, u16* __restrict__ wqkvT,
                       const float* __restrict__ w_out, u16* __restrict__ woutT) {
    __shared__ float t[32][33];
    const int bid = blockIdx.x, tid = threadIdx.x;
    if (bid < 2048) {
        const int i = bid * 256 + tid;           // i < 524288
        const float4* s = (const float4*)x + (size_t)i * 2;
        float4 a = s[0], b = s[1];
        u16x8 v;
        v[0] = bf16_rn(a.x); v[1] = bf16_rn(a.y); v[2] = bf16_rn(a.z); v[3] = bf16_rn(a.w);
        v[4] = bf16_rn(b.x); v[5] = bf16_rn(b.y); v[6] = bf16_rn(b.z); v[7] = bf16_rn(b.w);
        *(u16x8*)(xb + (size_t)i * 8) = v;
        return;
    }
    const float* src; u16* dst; int R, C, bxi, byi;
    if (bid < 5120) {
        const int tb = bid - 2048;               // 96 x-blocks, 32 y-blocks
        src = w_qkv; dst = wqkvT; R = 1024; C = 3072;
        bxi = tb % 96; byi = tb / 96;
    } else {
        const int tb = bid - 5120;               // 32 x-blocks, 32 y-blocks
        src = w_out; dst = woutT; R = 1024; C = 1024;
        bxi = tb % 32; byi = tb / 32;
    }
    const int tx = tid & 31, ty = tid >> 5;      // (32,8) remap
    const int bx = bxi * 32, by = byi * 32;
#pragma unroll
    for (int j = 0; j < 32; j += 8)
        t[ty + j][tx] = src[(size_t)(by + ty + j) * C + bx + tx];
    __syncthreads();
#pragma unroll
    for (int j = 0; j < 32; j += 8)
        dst[(size_t)(bx + ty + j) * R + by + tx] = bf16_rn(t[tx][ty + j]);
}

// ---- kernel 3/5: bf16 GEMM, C = A[M][K] * Bt[N][K]^T ---------------------
// m97 pattern (R15-proven): 128x128 tile, BK=32, global_load_lds(16B) into
// linear LDS, double-buffered with counted vmcnt(4) + raw s_barrier.
// MODE 0: scatter bf16 into qkv planes (Q pre-scaled by (1/8)*log2(e)).
// MODE 1: f32 row-major out.

template <int MODE>
__launch_bounds__(256, 2)
__global__ void k_gemm(const u16* __restrict__ A, const u16* __restrict__ Bt,
                       void* __restrict__ outp, int M, int N, int K) {
    __shared__ __align__(16) u16 As[2][128 * 32];
    __shared__ __align__(16) u16 Bs[2][128 * 32];
    const int tid = threadIdx.x;
    const int l = tid & 63, wv = tid >> 6;
    const int wr = wv >> 1, wc = wv & 1;
    const int l15 = l & 15, lg = l >> 4;
    const int m0 = blockIdx.y * 128, n0 = blockIdx.x * 128;
    const int NT = K >> 5;

    const f32x4 fzero = {0.f, 0.f, 0.f, 0.f};
    f32x4 acc[4][4];
#pragma unroll
    for (int m = 0; m < 4; m++)
#pragma unroll
        for (int n = 0; n < 4; n++) acc[m][n] = fzero;

    const int grow0 = wv * 32 + (l >> 2);
    const int gcol = (l & 3) * 8;

    auto stage = [&](int buf, int kt) {
        const size_t ko = (size_t)kt * 32 + gcol;
        glds16(A  + (size_t)(m0 + grow0) * K + ko,      &As[buf][wv * 1024]);
        glds16(A  + (size_t)(m0 + grow0 + 16) * K + ko, &As[buf][wv * 1024 + 512]);
        glds16(Bt + (size_t)(n0 + grow0) * K + ko,      &Bs[buf][wv * 1024]);
        glds16(Bt + (size_t)(n0 + grow0 + 16) * K + ko, &Bs[buf][wv * 1024 + 512]);
    };

    stage(0, 0);
    int cur = 0;
    for (int kt = 0; kt < NT; ++kt) {
        if (kt + 1 < NT) {
            stage(cur ^ 1, kt + 1);
            asm volatile("s_waitcnt vmcnt(4)" ::: "memory");
        } else {
            asm volatile("s_waitcnt vmcnt(0)" ::: "memory");
        }
        __builtin_amdgcn_s_barrier();
        u16x8 af[4], bfv[4];
#pragma unroll
        for (int m = 0; m < 4; m++)
            af[m] = *(const u16x8*)(&As[cur][(wr * 64 + m * 16 + l15) * 32 + lg * 8]);
#pragma unroll
        for (int n = 0; n < 4; n++)
            bfv[n] = *(const u16x8*)(&Bs[cur][(wc * 64 + n * 16 + l15) * 32 + lg * 8]);
#pragma unroll
        for (int m = 0; m < 4; m++)
#pragma unroll
            for (int n = 0; n < 4; n++)
                acc[m][n] = __builtin_amdgcn_mfma_f32_16x16x32_bf16(
                    as_bf(af[m]), as_bf(bfv[n]), acc[m][n], 0, 0, 0);
        __builtin_amdgcn_s_barrier();
        cur ^= 1;
    }

    if (MODE == 0) {
        u16* qkv = (u16*)outp;
#pragma unroll
        for (int m = 0; m < 4; m++) {
            const int rb = m0 + wr * 64 + m * 16 + lg * 4;
#pragma unroll
            for (int n = 0; n < 4; n++) {
                const int c = n0 + wc * 64 + n * 16;
                const int t = c >> 10, h = (c >> 6) & 15, d0 = (c & 63) + l15;
                const float scl = (t == 0) ? 0.18033688011112042f : 1.0f;
#pragma unroll
                for (int i = 0; i < 4; i++) {
                    const int r = rb + i;
                    const int b = r >> 11, s = r & 2047;
                    qkv[((((size_t)t * 2 + b) * 16 + h) * 2048 + s) * 64 + d0] =
                        bf16_rn(acc[m][n][i] * scl);
                }
            }
        }
    } else {
        float* O = (float*)outp;
#pragma unroll
        for (int m = 0; m < 4; m++) {
            const int rb = m0 + wr * 64 + m * 16 + lg * 4;
#pragma unroll
            for (int n = 0; n < 4; n++) {
                const int c = n0 + wc * 64 + n * 16 + l15;
#pragma unroll
                for (int i = 0; i < 4; i++)
                    O[(size_t)(rb + i) * N + c] = acc[m][n][i];
            }
        }
    }
}

// ---- kernel 4: causal flash attention (swapped-QK, KVBLK=64) -------------
// R19 = R18 reordered into HALF-SEQUENCED softmax: the sa half (QK, mask,
// exp2, sum, pack, PV ks0/1) completes before sb starts. sa/sb never
// co-live (-16 regs) and pk splits into pka/pkb (-8 regs): peak live drops
// ~190 -> ~150, targeting 3 waves/SIMD under launch_bounds(256,3).
// R7's regression came from splitting the V-transpose (3x bank conflicts);
// here the full-width v_perm transpose and R12's one-iteration-ahead V
// prefetch are kept intact. Fixed-max softmax p = exp2(s-12);
// permlane32_swap B-frag exchange; grid 1024.
// Tripwire: VGPR collapse / WRITE_SIZE >> 8MB = spill -> revert to R18.

__launch_bounds__(256, 3)
__global__ void k_attn(const u16* __restrict__ qkv, u16* __restrict__ ab) {
    __shared__ __align__(16) char arena[4][9216];  // per wave: V^T u16[64][72] | Opart f32[32][64]
    __shared__ float MLs[4][64];
    const int tid = threadIdx.x, l = tid & 63, wv = tid >> 6;
    const int q = l & 31, h = l >> 5;
    const int bid = blockIdx.x;
    const int bh = bid & 31;           // xcd = bh&7 -> 4 heads per XCD L2
    const int pp = bid >> 5;           // 0..31, pair {pp, 63-pp}
    const int b = bh >> 4, hd = bh & 15;
    const size_t plane = (size_t)2048 * 64;
    const u16* Qg = qkv + ((size_t)(0 + b) * 16 + hd) * plane;
    const u16* Kg = qkv + ((size_t)(2 + b) * 16 + hd) * plane;
    const u16* Vg = qkv + ((size_t)(4 + b) * 16 + hd) * plane;
    u16* VT = (u16*)arena[wv];

    const int g = l & 7, qd = l >> 3;
    const u16* Kbase = Kg + (size_t)q * 64 + 8 * h;
    const u16* Vbase = Vg + (size_t)(8 * qd) * 64 + 8 * g;
    // swizzled V^T row index F(d) = 8*(d>>3) + ((d&7) ^ ((d>>3)&7))
    const int Fq0 = 8 * (q >> 3) + ((q & 7) ^ ((q >> 3) & 7));
    const int d1 = q + 32;
    const int Fq1 = 8 * (d1 >> 3) + ((d1 & 7) ^ ((d1 >> 3) & 7));
    const u16* vr0 = VT + Fq0 * 72 + 8 * h;
    const u16* vr1 = VT + Fq1 * 72 + 8 * h;
    const float FIXM = 12.0f;          // fixed softmax max (log2 domain)

    for (int ph = 0; ph < 2; ++ph) {
        const int qt = ph ? 63 - pp : pp;
        const int q0 = qt * 32, qg = q0 + q;
        const int n64 = (qt >> 1) + 1;   // # of 64-kv causal tiles

        u16x8 qf[4];
#pragma unroll
        for (int s = 0; s < 4; ++s)
            qf[s] = *(const u16x8*)(Qg + (size_t)(q0 + q) * 64 + s * 16 + 8 * h);

        f32x16 oacc0 = 0, oacc1 = 0;     // O^T d 0..31 / 32..63 (cols = q)
        float l_run = 0.f;               // this lane's half-row sum

        u16x8 vK[8], vV[8];              // prefetched K,V for the NEXT tile
        if (wv < n64) {
#pragma unroll
            for (int s = 0; s < 4; ++s) {
                vK[s]     = *(const u16x8*)(Kbase + (size_t)(wv * 64) * 64 + s * 16);
                vK[4 + s] = *(const u16x8*)(Kbase + (size_t)(wv * 64 + 32) * 64 + s * 16);
            }
#pragma unroll
            for (int j = 0; j < 8; ++j)
                vV[j] = *(const u16x8*)(Vbase + (size_t)(wv * 64 + j) * 64);
        }

        for (int t = wv; t < n64; t += 4) {
            const int kv0 = t * 64;
            const bool diag = (t == n64 - 1);
            const bool more = (t + 4 < n64);
            // ======== sa half (kv rows 0..31) ========
            f32x16 sa = 0;
            __builtin_amdgcn_s_setprio(1);
#pragma unroll
            for (int s = 0; s < 4; ++s)
                sa = __builtin_amdgcn_mfma_f32_32x32x16_bf16(as_bf(vK[s]), as_bf(qf[s]), sa, 0, 0, 0);
            __builtin_amdgcn_s_setprio(0);
            // ---- stage V^T via v_perm_b32 (full 8-row, b128 writes) ----
            {
                u32x4 vw[8];
#pragma unroll
                for (int r = 0; r < 8; ++r) vw[r] = __builtin_bit_cast(u32x4, vV[r]);
#pragma unroll
                for (int j = 0; j < 8; ++j) {
                    const u32 selc = (j & 1) ? 0x07060302u : 0x05040100u;
                    const int jr = j >> 1;
                    u32x4 cw;
#pragma unroll
                    for (int w = 0; w < 4; ++w)
                        cw[w] = __builtin_amdgcn_perm(vw[2 * w + 1][jr], vw[2 * w][jr], selc);
                    *(u32x4*)(VT + (size_t)(8 * g + (j ^ g)) * 72 + 8 * qd) = cw;
                }
            }
            // ---- prefetch V(t+4) and K rows 0..31 (both just died) ----
            if (more) {
#pragma unroll
                for (int j = 0; j < 8; ++j)
                    vV[j] = *(const u16x8*)(Vbase + (size_t)((t + 4) * 64 + j) * 64);
#pragma unroll
                for (int s = 0; s < 4; ++s)
                    vK[s] = *(const u16x8*)(Kbase + (size_t)((t + 4) * 64) * 64 + s * 16);
            }
            // ---- sa softmax ----
            if (diag) {
#pragma unroll
                for (int r = 0; r < 16; ++r) {
                    const int kg = kv0 + (r & 3) + 8 * (r >> 2) + 4 * h;
                    if (kg > qg) sa[r] = -__builtin_inff();
                }
            }
#pragma unroll
            for (int r = 0; r < 16; ++r) sa[r] = exp2f(sa[r] - FIXM);
            {
                float ts[4];
#pragma unroll
                for (int i = 0; i < 4; ++i)
                    ts[i] = (sa[i] + sa[i + 4]) + (sa[i + 8] + sa[i + 12]);
                l_run += (ts[0] + ts[2]) + (ts[1] + ts[3]);
            }
            u32 pka[8];
#pragma unroll
            for (int i = 0; i < 8; ++i) pka[i] = cvt_pk_bf16(sa[2 * i], sa[2 * i + 1]);
            // ---- PV ks=0,1 ----
#pragma unroll
            for (int ks = 0; ks < 2; ++ks) {
                u32 w0 = pka[4 * ks],     w1 = pka[4 * ks + 1];
                u32 w2 = pka[4 * ks + 2], w3 = pka[4 * ks + 3];
                asm("v_permlane32_swap_b32 %0, %1" : "+v"(w0), "+v"(w2));
                asm("v_permlane32_swap_b32 %0, %1" : "+v"(w1), "+v"(w3));
                const u16x8 pb = __builtin_bit_cast(u16x8, (u32x4){w0, w1, w2, w3});
                const u16x8 va0 = *(const u16x8*)(vr0 + ks * 16);
                const u16x8 va1 = *(const u16x8*)(vr1 + ks * 16);
                __builtin_amdgcn_s_setprio(1);
                oacc0 = __builtin_amdgcn_mfma_f32_32x32x16_bf16(as_bf(va0), as_bf(pb), oacc0, 0, 0, 0);
                oacc1 = __builtin_amdgcn_mfma_f32_32x32x16_bf16(as_bf(va1), as_bf(pb), oacc1, 0, 0, 0);
                __builtin_amdgcn_s_setprio(0);
            }
            // ======== sb half (kv rows 32..63) ========
            f32x16 sb = 0;
            __builtin_amdgcn_s_setprio(1);
#pragma unroll
            for (int s = 0; s < 4; ++s)
                sb = __builtin_amdgcn_mfma_f32_32x32x16_bf16(as_bf(vK[4 + s]), as_bf(qf[s]), sb, 0, 0, 0);
            __builtin_amdgcn_s_setprio(0);
            // ---- prefetch K rows 32..63 (vK[4..7] just died) ----
            if (more) {
#pragma unroll
                for (int s = 0; s < 4; ++s)
                    vK[4 + s] = *(const u16x8*)(Kbase + (size_t)((t + 4) * 64 + 32) * 64 + s * 16);
            }
            // ---- sb softmax ----
            if (diag) {
#pragma unroll
                for (int r = 0; r < 16; ++r) {
                    const int kg = kv0 + 32 + (r & 3) + 8 * (r >> 2) + 4 * h;
                    if (kg > qg) sb[r] = -__builtin_inff();
                }
            }
#pragma unroll
            for (int r = 0; r < 16; ++r) sb[r] = exp2f(sb[r] - FIXM);
            {
                float ts[4];
#pragma unroll
                for (int i = 0; i < 4; ++i)
                    ts[i] = (sb[i] + sb[i + 4]) + (sb[i + 8] + sb[i + 12]);
                l_run += (ts[0] + ts[2]) + (ts[1] + ts[3]);
            }
            u32 pkb[8];
#pragma unroll
            for (int i = 0; i < 8; ++i) pkb[i] = cvt_pk_bf16(sb[2 * i], sb[2 * i + 1]);
            // ---- PV ks=2,3 ----
#pragma unroll
            for (int ks = 0; ks < 2; ++ks) {
                u32 w0 = pkb[4 * ks],     w1 = pkb[4 * ks + 1];
                u32 w2 = pkb[4 * ks + 2], w3 = pkb[4 * ks + 3];
                asm("v_permlane32_swap_b32 %0, %1" : "+v"(w0), "+v"(w2));
                asm("v_permlane32_swap_b32 %0, %1" : "+v"(w1), "+v"(w3));
                const u16x8 pb = __builtin_bit_cast(u16x8, (u32x4){w0, w1, w2, w3});
                const u16x8 va0 = *(const u16x8*)(vr0 + (2 + ks) * 16);
                const u16x8 va1 = *(const u16x8*)(vr1 + (2 + ks) * 16);
                __builtin_amdgcn_s_setprio(1);
                oacc0 = __builtin_amdgcn_mfma_f32_32x32x16_bf16(as_bf(va0), as_bf(pb), oacc0, 0, 0, 0);
                oacc1 = __builtin_amdgcn_mfma_f32_32x32x16_bf16(as_bf(va1), as_bf(pb), oacc1, 0, 0, 0);
                __builtin_amdgcn_s_setprio(0);
            }
        }
        asm volatile("" ::: "memory");  // order VT reads before Opart overwrite
        float* Op = (float*)arena[wv];
#pragma unroll
        for (int r = 0; r < 16; ++r) {
            const int dr = (r & 3) + 8 * (r >> 2) + 4 * h;
            Op[q * 64 + ((dr + 2 * q) & 63)]      = oacc0[r];
            Op[q * 64 + ((dr + 32 + 2 * q) & 63)] = oacc1[r];
        }
        MLs[wv][l] = l_run;
        __syncthreads();
        const int tq = tid >> 3, dblk = (tid & 7) * 8;
        float L = 0.f;
#pragma unroll
        for (int w = 0; w < 4; ++w) L += MLs[w][tq] + MLs[w][32 + tq];
        const float inv = 1.f / L;
        u16x8 outv;
#pragma unroll
        for (int j = 0; j < 8; ++j) {
            const int d = dblk + j;
            float acc = 0.f;
#pragma unroll
            for (int w = 0; w < 4; ++w)
                acc += ((const float*)arena[w])[tq * 64 + ((d + 2 * tq) & 63)];
            outv[j] = bf16_rn(acc * inv);
        }
        *(u16x8*)(ab + (size_t)(b * 2048 + q0 + tq) * 1024 + hd * 64 + dblk) = outv;
        __syncthreads();  // arenas must be fully read before next phase reuses them
    }
}

// ---- launch --------------------------------------------------------------

extern "C" void kernel_launch(void* const* d_in, const int* in_sizes, int n_in,
                              void* d_out, int out_size, void* d_ws, size_t ws_size,
                              hipStream_t stream) {
    const float* x     = (const float*)d_in[0];
    // d_in[1] = mask: exact causal tril, encoded structurally in k_attn
    const float* w_qkv = (const float*)d_in[2];
    const float* w_out = (const float*)d_in[3];
    float* out = (float*)d_out;
    u16* ws = (u16*)d_ws;

    u16* xb    = ws;
    u16* wqkvT = ws + 4194304;
    u16* woutT = ws + 7340032;
    u16* qkvb  = ws + 8388608;
    u16* abuf  = ws;   // alias xb: x is dead after the QKV GEMM

    k_prep<<<6144, 256, 0, stream>>>(x, xb, w_qkv, wqkvT, w_out, woutT);
    k_gemm<0><<<dim3(24, 32), 256, 0, stream>>>(xb, wqkvT, qkvb, 4096, 3072, 1024);
    k_attn<<<1024, 256, 0, stream>>>(qkvb, abuf);
    k_gemm<1><<<dim3(8, 32), 256, 0, stream>>>(abuf, woutT, out, 4096, 1024, 1024);
}

// Round 20
// 122.740 us; speedup vs baseline: 1.4627x; 1.4627x over previous
//
#include <hip/hip_runtime.h>

typedef unsigned short u16;
typedef unsigned int u32;
typedef u16 u16x8 __attribute__((ext_vector_type(8)));
typedef u16 u16x4 __attribute__((ext_vector_type(4)));
typedef u32 u32x4 __attribute__((ext_vector_type(4)));
typedef __bf16 bf16x8 __attribute__((ext_vector_type(8)));
typedef float f32x4 __attribute__((ext_vector_type(4)));
typedef float f32x16 __attribute__((ext_vector_type(16)));

// ---- helpers -------------------------------------------------------------

static __device__ __forceinline__ u16 bf16_rn(float f) {
    union { float f; u32 u; } a; a.f = f;
    u32 u = a.u;
    return (u16)((u + 0x7FFFu + ((u >> 16) & 1u)) >> 16);  // RNE
}

static __device__ __forceinline__ bf16x8 as_bf(u16x8 v) {
    return __builtin_bit_cast(bf16x8, v);
}

static __device__ __forceinline__ u32 cvt_pk_bf16(float lo, float hi) {
    u32 r;
    asm("v_cvt_pk_bf16_f32 %0, %1, %2" : "=v"(r) : "v"(lo), "v"(hi));
    return r;
}

static __device__ __forceinline__ void glds16(const u16* g, u16* lds) {
    __builtin_amdgcn_global_load_lds(
        (const __attribute__((address_space(1))) void*)g,
        (__attribute__((address_space(3))) void*)lds, 16, 0, 0);
}

// ---- kernel 1: fused preprocessing ----------------------------------------
// bid < 2048        : x f32 -> bf16 (8 elems/thread)
// 2048 <= bid < 5120: w_qkv [1024][3072] -> wqkvT [3072][1024] bf16
// bid >= 5120       : w_out [1024][1024] -> woutT [1024][1024] bf16

__global__ void k_prep(const float* __restrict__ x, u16* __restrict__ xb,
                       const float* __restrict__ w_qkv, u16* __restrict__ wqkvT,
                       const float* __restrict__ w_out, u16* __restrict__ woutT) {
    __shared__ float t[32][33];
    const int bid = blockIdx.x, tid = threadIdx.x;
    if (bid < 2048) {
        const int i = bid * 256 + tid;           // i < 524288
        const float4* s = (const float4*)x + (size_t)i * 2;
        float4 a = s[0], b = s[1];
        u16x8 v;
        v[0] = bf16_rn(a.x); v[1] = bf16_rn(a.y); v[2] = bf16_rn(a.z); v[3] = bf16_rn(a.w);
        v[4] = bf16_rn(b.x); v[5] = bf16_rn(b.y); v[6] = bf16_rn(b.z); v[7] = bf16_rn(b.w);
        *(u16x8*)(xb + (size_t)i * 8) = v;
        return;
    }
    const float* src; u16* dst; int R, C, bxi, byi;
    if (bid < 5120) {
        const int tb = bid - 2048;               // 96 x-blocks, 32 y-blocks
        src = w_qkv; dst = wqkvT; R = 1024; C = 3072;
        bxi = tb % 96; byi = tb / 96;
    } else {
        const int tb = bid - 5120;               // 32 x-blocks, 32 y-blocks
        src = w_out; dst = woutT; R = 1024; C = 1024;
        bxi = tb % 32; byi = tb / 32;
    }
    const int tx = tid & 31, ty = tid >> 5;      // (32,8) remap
    const int bx = bxi * 32, by = byi * 32;
#pragma unroll
    for (int j = 0; j < 32; j += 8)
        t[ty + j][tx] = src[(size_t)(by + ty + j) * C + bx + tx];
    __syncthreads();
#pragma unroll
    for (int j = 0; j < 32; j += 8)
        dst[(size_t)(bx + ty + j) * R + by + tx] = bf16_rn(t[tx][ty + j]);
}

// ---- kernel 3/5: bf16 GEMM, C = A[M][K] * Bt[N][K]^T ---------------------
// m97 pattern (R15-proven): 128x128 tile, BK=32, global_load_lds(16B) into
// linear LDS, double-buffered with counted vmcnt(4) + raw s_barrier.
// MODE 0: scatter bf16 into qkv planes (Q pre-scaled by (1/8)*log2(e)).
// MODE 1: f32 row-major out.

template <int MODE>
__launch_bounds__(256, 2)
__global__ void k_gemm(const u16* __restrict__ A, const u16* __restrict__ Bt,
                       void* __restrict__ outp, int M, int N, int K) {
    __shared__ __align__(16) u16 As[2][128 * 32];
    __shared__ __align__(16) u16 Bs[2][128 * 32];
    const int tid = threadIdx.x;
    const int l = tid & 63, wv = tid >> 6;
    const int wr = wv >> 1, wc = wv & 1;
    const int l15 = l & 15, lg = l >> 4;
    const int m0 = blockIdx.y * 128, n0 = blockIdx.x * 128;
    const int NT = K >> 5;

    const f32x4 fzero = {0.f, 0.f, 0.f, 0.f};
    f32x4 acc[4][4];
#pragma unroll
    for (int m = 0; m < 4; m++)
#pragma unroll
        for (int n = 0; n < 4; n++) acc[m][n] = fzero;

    const int grow0 = wv * 32 + (l >> 2);
    const int gcol = (l & 3) * 8;

    auto stage = [&](int buf, int kt) {
        const size_t ko = (size_t)kt * 32 + gcol;
        glds16(A  + (size_t)(m0 + grow0) * K + ko,      &As[buf][wv * 1024]);
        glds16(A  + (size_t)(m0 + grow0 + 16) * K + ko, &As[buf][wv * 1024 + 512]);
        glds16(Bt + (size_t)(n0 + grow0) * K + ko,      &Bs[buf][wv * 1024]);
        glds16(Bt + (size_t)(n0 + grow0 + 16) * K + ko, &Bs[buf][wv * 1024 + 512]);
    };

    stage(0, 0);
    int cur = 0;
    for (int kt = 0; kt < NT; ++kt) {
        if (kt + 1 < NT) {
            stage(cur ^ 1, kt + 1);
            asm volatile("s_waitcnt vmcnt(4)" ::: "memory");
        } else {
            asm volatile("s_waitcnt vmcnt(0)" ::: "memory");
        }
        __builtin_amdgcn_s_barrier();
        u16x8 af[4], bfv[4];
#pragma unroll
        for (int m = 0; m < 4; m++)
            af[m] = *(const u16x8*)(&As[cur][(wr * 64 + m * 16 + l15) * 32 + lg * 8]);
#pragma unroll
        for (int n = 0; n < 4; n++)
            bfv[n] = *(const u16x8*)(&Bs[cur][(wc * 64 + n * 16 + l15) * 32 + lg * 8]);
#pragma unroll
        for (int m = 0; m < 4; m++)
#pragma unroll
            for (int n = 0; n < 4; n++)
                acc[m][n] = __builtin_amdgcn_mfma_f32_16x16x32_bf16(
                    as_bf(af[m]), as_bf(bfv[n]), acc[m][n], 0, 0, 0);
        __builtin_amdgcn_s_barrier();
        cur ^= 1;
    }

    if (MODE == 0) {
        u16* qkv = (u16*)outp;
#pragma unroll
        for (int m = 0; m < 4; m++) {
            const int rb = m0 + wr * 64 + m * 16 + lg * 4;
#pragma unroll
            for (int n = 0; n < 4; n++) {
                const int c = n0 + wc * 64 + n * 16;
                const int t = c >> 10, h = (c >> 6) & 15, d0 = (c & 63) + l15;
                const float scl = (t == 0) ? 0.18033688011112042f : 1.0f;
#pragma unroll
                for (int i = 0; i < 4; i++) {
                    const int r = rb + i;
                    const int b = r >> 11, s = r & 2047;
                    qkv[((((size_t)t * 2 + b) * 16 + h) * 2048 + s) * 64 + d0] =
                        bf16_rn(acc[m][n][i] * scl);
                }
            }
        }
    } else {
        float* O = (float*)outp;
#pragma unroll
        for (int m = 0; m < 4; m++) {
            const int rb = m0 + wr * 64 + m * 16 + lg * 4;
#pragma unroll
            for (int n = 0; n < 4; n++) {
                const int c = n0 + wc * 64 + n * 16 + l15;
#pragma unroll
                for (int i = 0; i < 4; i++)
                    O[(size_t)(rb + i) * N + c] = acc[m][n][i];
            }
        }
    }
}

// ---- kernel 4: causal flash attention (swapped-QK, KVBLK=64) -------------
// FINAL (R17 config, 122.79us): R15 body — V prefetched one full iteration
// ahead, fixed-max softmax p = exp2(s - 12), permlane32_swap B-frag
// exchange, grid 1024, launch_bounds(256,2) (every tighter bound spilled:
// R5/R8/R19). Invariant to occupancy/ILP/VALU-count changes (R9-R18 nulls);
// the ~63us floor is the per-tile dependency chain at 2 waves/SIMD.

__launch_bounds__(256, 2)
__global__ void k_attn(const u16* __restrict__ qkv, u16* __restrict__ ab) {
    __shared__ __align__(16) char arena[4][9216];  // per wave: V^T u16[64][72] | Opart f32[32][64]
    __shared__ float MLs[4][64];
    const int tid = threadIdx.x, l = tid & 63, wv = tid >> 6;
    const int q = l & 31, h = l >> 5;
    const int bid = blockIdx.x;
    const int bh = bid & 31;           // xcd = bh&7 -> 4 heads per XCD L2
    const int pp = bid >> 5;           // 0..31, pair {pp, 63-pp}
    const int b = bh >> 4, hd = bh & 15;
    const size_t plane = (size_t)2048 * 64;
    const u16* Qg = qkv + ((size_t)(0 + b) * 16 + hd) * plane;
    const u16* Kg = qkv + ((size_t)(2 + b) * 16 + hd) * plane;
    const u16* Vg = qkv + ((size_t)(4 + b) * 16 + hd) * plane;
    u16* VT = (u16*)arena[wv];

    const int g = l & 7, qd = l >> 3;
    const u16* Kbase = Kg + (size_t)q * 64 + 8 * h;
    const u16* Vbase = Vg + (size_t)(8 * qd) * 64 + 8 * g;
    // swizzled V^T row index F(d) = 8*(d>>3) + ((d&7) ^ ((d>>3)&7))
    const int Fq0 = 8 * (q >> 3) + ((q & 7) ^ ((q >> 3) & 7));
    const int d1 = q + 32;
    const int Fq1 = 8 * (d1 >> 3) + ((d1 & 7) ^ ((d1 >> 3) & 7));
    const u16* vr0 = VT + Fq0 * 72 + 8 * h;
    const u16* vr1 = VT + Fq1 * 72 + 8 * h;
    const float FIXM = 12.0f;          // fixed softmax max (log2 domain)

    for (int ph = 0; ph < 2; ++ph) {
        const int qt = ph ? 63 - pp : pp;
        const int q0 = qt * 32, qg = q0 + q;
        const int n64 = (qt >> 1) + 1;   // # of 64-kv causal tiles

        u16x8 qf[4];
#pragma unroll
        for (int s = 0; s < 4; ++s)
            qf[s] = *(const u16x8*)(Qg + (size_t)(q0 + q) * 64 + s * 16 + 8 * h);

        f32x16 oacc0 = 0, oacc1 = 0;     // O^T d 0..31 / 32..63 (cols = q)
        float l_run = 0.f;               // this lane's half-row sum

        u16x8 vK[8], vV[8];              // prefetched K,V for the NEXT tile
        if (wv < n64) {
#pragma unroll
            for (int s = 0; s < 4; ++s) {
                vK[s]     = *(const u16x8*)(Kbase + (size_t)(wv * 64) * 64 + s * 16);
                vK[4 + s] = *(const u16x8*)(Kbase + (size_t)(wv * 64 + 32) * 64 + s * 16);
            }
#pragma unroll
            for (int j = 0; j < 8; ++j)
                vV[j] = *(const u16x8*)(Vbase + (size_t)(wv * 64 + j) * 64);
        }

        for (int t = wv; t < n64; t += 4) {
            const int kv0 = t * 64;
            f32x16 sa = 0, sb = 0;
            __builtin_amdgcn_s_setprio(1);
#pragma unroll
            for (int s = 0; s < 4; ++s)
                sa = __builtin_amdgcn_mfma_f32_32x32x16_bf16(as_bf(vK[s]), as_bf(qf[s]), sa, 0, 0, 0);
#pragma unroll
            for (int s = 0; s < 4; ++s)
                sb = __builtin_amdgcn_mfma_f32_32x32x16_bf16(as_bf(vK[4 + s]), as_bf(qf[s]), sb, 0, 0, 0);
            __builtin_amdgcn_s_setprio(0);
#pragma unroll
            for (int j = 0; j < 8; ++j) {
                u16x8 col;
#pragma unroll
                for (int r = 0; r < 8; ++r) col[r] = vV[r][j];
                *(u16x8*)(VT + (size_t)(8 * g + (j ^ g)) * 72 + 8 * qd) = col;
            }
            if (t + 4 < n64) {
#pragma unroll
                for (int s = 0; s < 4; ++s) {
                    vK[s]     = *(const u16x8*)(Kbase + (size_t)((t + 4) * 64) * 64 + s * 16);
                    vK[4 + s] = *(const u16x8*)(Kbase + (size_t)((t + 4) * 64 + 32) * 64 + s * 16);
                }
#pragma unroll
                for (int j = 0; j < 8; ++j)
                    vV[j] = *(const u16x8*)(Vbase + (size_t)((t + 4) * 64 + j) * 64);
            }
            if (t == n64 - 1) {
#pragma unroll
                for (int r = 0; r < 16; ++r) {
                    const int kg = kv0 + (r & 3) + 8 * (r >> 2) + 4 * h;
                    if (kg > qg) sa[r] = -__builtin_inff();
                    if (kg + 32 > qg) sb[r] = -__builtin_inff();
                }
            }
#pragma unroll
            for (int r = 0; r < 16; ++r) sa[r] = exp2f(sa[r] - FIXM);
#pragma unroll
            for (int r = 0; r < 16; ++r) sb[r] = exp2f(sb[r] - FIXM);
            float ts[8];
#pragma unroll
            for (int i = 0; i < 8; ++i)
                ts[i] = (sa[i] + sa[i + 8]) + (sb[i] + sb[i + 8]);
#pragma unroll
            for (int i = 0; i < 4; ++i) ts[i] += ts[i + 4];
            l_run += (ts[0] + ts[2]) + (ts[1] + ts[3]);
            u32 pk[16];
#pragma unroll
            for (int i = 0; i < 8; ++i) pk[i]     = cvt_pk_bf16(sa[2 * i], sa[2 * i + 1]);
#pragma unroll
            for (int i = 0; i < 8; ++i) pk[8 + i] = cvt_pk_bf16(sb[2 * i], sb[2 * i + 1]);
#pragma unroll
            for (int ks = 0; ks < 4; ++ks) {
                const int base = (ks >> 1) * 8 + 4 * (ks & 1);
                u32 w0 = pk[base],     w1 = pk[base + 1];
                u32 w2 = pk[base + 2], w3 = pk[base + 3];
                asm("v_permlane32_swap_b32 %0, %1" : "+v"(w0), "+v"(w2));
                asm("v_permlane32_swap_b32 %0, %1" : "+v"(w1), "+v"(w3));
                const u16x8 pb = __builtin_bit_cast(u16x8, (u32x4){w0, w1, w2, w3});
                const u16x8 va0 = *(const u16x8*)(vr0 + ks * 16);
                const u16x8 va1 = *(const u16x8*)(vr1 + ks * 16);
                __builtin_amdgcn_s_setprio(1);
                oacc0 = __builtin_amdgcn_mfma_f32_32x32x16_bf16(as_bf(va0), as_bf(pb), oacc0, 0, 0, 0);
                oacc1 = __builtin_amdgcn_mfma_f32_32x32x16_bf16(as_bf(va1), as_bf(pb), oacc1, 0, 0, 0);
                __builtin_amdgcn_s_setprio(0);
            }
        }
        asm volatile("" ::: "memory");  // order VT reads before Opart overwrite
        float* Op = (float*)arena[wv];
#pragma unroll
        for (int r = 0; r < 16; ++r) {
            const int dr = (r & 3) + 8 * (r >> 2) + 4 * h;
            Op[q * 64 + ((dr + 2 * q) & 63)]      = oacc0[r];
            Op[q * 64 + ((dr + 32 + 2 * q) & 63)] = oacc1[r];
        }
        MLs[wv][l] = l_run;
        __syncthreads();
        const int tq = tid >> 3, dblk = (tid & 7) * 8;
        float L = 0.f;
#pragma unroll
        for (int w = 0; w < 4; ++w) L += MLs[w][tq] + MLs[w][32 + tq];
        const float inv = 1.f / L;
        u16x8 outv;
#pragma unroll
        for (int j = 0; j < 8; ++j) {
            const int d = dblk + j;
            float acc = 0.f;
#pragma unroll
            for (int w = 0; w < 4; ++w)
                acc += ((const float*)arena[w])[tq * 64 + ((d + 2 * tq) & 63)];
            outv[j] = bf16_rn(acc * inv);
        }
        *(u16x8*)(ab + (size_t)(b * 2048 + q0 + tq) * 1024 + hd * 64 + dblk) = outv;
        __syncthreads();  // arenas must be fully read before next phase reuses them
    }
}

// ---- launch --------------------------------------------------------------

extern "C" void kernel_launch(void* const* d_in, const int* in_sizes, int n_in,
                              void* d_out, int out_size, void* d_ws, size_t ws_size,
                              hipStream_t stream) {
    const float* x     = (const float*)d_in[0];
    // d_in[1] = mask: exact causal tril, encoded structurally in k_attn
    const float* w_qkv = (const float*)d_in[2];
    const float* w_out = (const float*)d_in[3];
    float* out = (float*)d_out;
    u16* ws = (u16*)d_ws;

    u16* xb    = ws;
    u16* wqkvT = ws + 4194304;
    u16* woutT = ws + 7340032;
    u16* qkvb  = ws + 8388608;
    u16* abuf  = ws;   // alias xb: x is dead after the QKV GEMM

    k_prep<<<6144, 256, 0, stream>>>(x, xb, w_qkv, wqkvT, w_out, woutT);
    k_gemm<0><<<dim3(24, 32), 256, 0, stream>>>(xb, wqkvT, qkvb, 4096, 3072, 1024);
    k_attn<<<1024, 256, 0, stream>>>(qkvb, abuf);
    k_gemm<1><<<dim3(8, 32), 256, 0, stream>>>(abuf, woutT, out, 4096, 1024, 1024);
}